// Round 1
// baseline (381.620 us; speedup 1.0000x reference)
//
#include <hip/hip_runtime.h>
#include <hip/hip_bf16.h>

// SpMM: out[r,:] = sum_{k: rows[k]==r} values[k] * weight[cols[k],:]  + bias
// values: f32[NNZ], weight: f32[IN_F, OUT_F], bias: f32[OUT_F],
// rows: i32[NNZ], cols: i32[NNZ], n_rows scalar. out: f32[n_rows, OUT_F].

// ---------------- Phase 1: histogram rows ----------------
__global__ void count_rows_kernel(const int* __restrict__ rows, int* __restrict__ counts, int nnz) {
    int i = blockIdx.x * blockDim.x + threadIdx.x;
    if (i < nnz) atomicAdd(&counts[rows[i]], 1);
}

// ---------------- Phase 2: exclusive scan (single block, 256 threads) ----------------
__global__ void scan_kernel(const int* __restrict__ counts, int* __restrict__ offsets, int n_rows) {
    __shared__ int partial[256];
    const int t = threadIdx.x;
    const int per = (n_rows + 255) / 256;
    const int base = t * per;
    int sum = 0;
    for (int j = 0; j < per; ++j) {
        int idx = base + j;
        if (idx < n_rows) sum += counts[idx];
    }
    partial[t] = sum;
    __syncthreads();
    // Hillis-Steele inclusive scan over 256 partials
    for (int off = 1; off < 256; off <<= 1) {
        int v = 0;
        if (t >= off) v = partial[t - off];
        __syncthreads();
        if (t >= off) partial[t] += v;
        __syncthreads();
    }
    int run = (t == 0) ? 0 : partial[t - 1];   // exclusive
    for (int j = 0; j < per; ++j) {
        int idx = base + j;
        if (idx < n_rows) {
            offsets[idx] = run;
            run += counts[idx];
        }
    }
    if (t == 255) offsets[n_rows] = run;
}

// ---------------- Phase 3: scatter nnz indices into row buckets ----------------
__global__ void scatter_kernel(const int* __restrict__ rows, int* __restrict__ cursor,
                               int* __restrict__ perm, int nnz) {
    int i = blockIdx.x * blockDim.x + threadIdx.x;
    if (i < nnz) {
        int p = atomicAdd(&cursor[rows[i]], 1);
        perm[p] = i;
    }
}

// ---------------- Phase 4: per-row gather + accumulate ----------------
// One block per output row; 128 threads x float4 = 512 output columns.
__global__ void accum_kernel(const float* __restrict__ values,
                             const float* __restrict__ weight,
                             const float* __restrict__ bias,
                             const int* __restrict__ cols,
                             const int* __restrict__ offsets,
                             const int* __restrict__ perm,
                             float* __restrict__ out, int out_f) {
    const int r = blockIdx.x;
    const int start = offsets[r];
    const int end   = offsets[r + 1];
    const int step  = blockDim.x * 4;

    for (int base = threadIdx.x * 4; base < out_f; base += step) {
        float4 acc = make_float4(0.f, 0.f, 0.f, 0.f);
        for (int p = start; p < end; ++p) {
            int k = perm[p];                 // wave-uniform: broadcast load
            float v = values[k];
            long long c = cols[k];
            float4 w = *(const float4*)(weight + c * (long long)out_f + base);
            acc.x += v * w.x;
            acc.y += v * w.y;
            acc.z += v * w.z;
            acc.w += v * w.w;
        }
        float4 b = *(const float4*)(bias + base);
        acc.x += b.x; acc.y += b.y; acc.z += b.z; acc.w += b.w;
        *(float4*)(out + (long long)r * out_f + base) = acc;
    }
}

// ---------------- Fallback (ws too small): bias-init + atomic scatter ----------------
__global__ void init_bias_kernel(const float* __restrict__ bias, float* __restrict__ out,
                                 int out_f, long long total) {
    long long i = (long long)blockIdx.x * blockDim.x + threadIdx.x;
    long long stride = (long long)gridDim.x * blockDim.x;
    for (; i < total; i += stride) out[i] = bias[(int)(i % out_f)];
}

__global__ void atomic_scatter_kernel(const float* __restrict__ values,
                                      const float* __restrict__ weight,
                                      const int* __restrict__ rows,
                                      const int* __restrict__ cols,
                                      float* __restrict__ out, int nnz, int out_f) {
    int gtid = blockIdx.x * blockDim.x + threadIdx.x;
    int wave = gtid >> 6;
    int lane = gtid & 63;
    if (wave >= nnz) return;
    float v = values[wave];
    int r = rows[wave];
    long long c = cols[wave];
    const float* wrow = weight + c * (long long)out_f;
    float* orow = out + (long long)r * out_f;
    for (int col = lane; col < out_f; col += 64) {
        atomicAdd(&orow[col], v * wrow[col]);
    }
}

extern "C" void kernel_launch(void* const* d_in, const int* in_sizes, int n_in,
                              void* d_out, int out_size, void* d_ws, size_t ws_size,
                              hipStream_t stream) {
    const float* values = (const float*)d_in[0];
    const float* weight = (const float*)d_in[1];
    const float* bias   = (const float*)d_in[2];
    const int*   rows   = (const int*)d_in[3];
    const int*   cols   = (const int*)d_in[4];

    const int nnz   = in_sizes[0];
    const int out_f = in_sizes[2];
    const int n_rows = out_size / out_f;
    float* out = (float*)d_out;

    // ws layout: counts[n_rows] | offsets[n_rows+1] | cursor[n_rows] | perm[nnz]
    size_t need = (size_t)(3 * n_rows + 1 + nnz) * sizeof(int);

    if (ws_size >= need) {
        int* counts  = (int*)d_ws;
        int* offsets = counts + n_rows;
        int* cursor  = offsets + n_rows + 1;
        int* perm    = cursor + n_rows;

        hipMemsetAsync(counts, 0, (size_t)n_rows * sizeof(int), stream);

        int blocks = (nnz + 255) / 256;
        count_rows_kernel<<<blocks, 256, 0, stream>>>(rows, counts, nnz);
        scan_kernel<<<1, 256, 0, stream>>>(counts, offsets, n_rows);
        hipMemcpyAsync(cursor, offsets, (size_t)n_rows * sizeof(int),
                       hipMemcpyDeviceToDevice, stream);
        scatter_kernel<<<blocks, 256, 0, stream>>>(rows, cursor, perm, nnz);
        accum_kernel<<<n_rows, 128, 0, stream>>>(values, weight, bias, cols,
                                                 offsets, perm, out, out_f);
    } else {
        long long total = (long long)n_rows * out_f;
        int ib_blocks = (int)((total + 255) / 256);
        if (ib_blocks > 4096) ib_blocks = 4096;
        init_bias_kernel<<<ib_blocks, 256, 0, stream>>>(bias, out, out_f, total);
        int waves_per_block = 256 / 64;
        int sc_blocks = (nnz + waves_per_block - 1) / waves_per_block;
        atomic_scatter_kernel<<<sc_blocks, 256, 0, stream>>>(values, weight, rows, cols,
                                                             out, nnz, out_f);
    }
}

// Round 2
// 323.347 us; speedup vs baseline: 1.1802x; 1.1802x over previous
//
#include <hip/hip_runtime.h>
#include <hip/hip_fp16.h>

// SpMM: out[r,:] = sum_{k: rows[k]==r} values[k] * weight[cols[k],:]  + bias
// Strategy: counting-sort nnz by row into (col,val) pairs; convert weight to
// fp16 in ws (halves gather bytes — the kernel is bytes-bound at the memory-
// hierarchy ceiling); one wave per output row gathers fp16 rows, f32 accum.

struct Pair { int c; float v; };

// ---- Fused: weight f32->f16 conversion (grid-stride, 8 floats/thread) + row histogram ----
__global__ void convert_count_kernel(const float* __restrict__ weight,
                                     __half* __restrict__ wf16, long long ngroups,
                                     const int* __restrict__ rows,
                                     int* __restrict__ counts, int nnz) {
    long long i = (long long)blockIdx.x * blockDim.x + threadIdx.x;
    if (i < nnz) atomicAdd(&counts[rows[(int)i]], 1);
    const float4* w4 = (const float4*)weight;
    float4* dst = (float4*)wf16;               // 16B = 8 halfs per group
    long long stride = (long long)gridDim.x * blockDim.x;
    for (long long g = i; g < ngroups; g += stride) {
        float4 a = w4[2 * g];
        float4 b = w4[2 * g + 1];
        union { __half2 h2[4]; float4 f4; } u;
        u.h2[0] = __floats2half2_rn(a.x, a.y);
        u.h2[1] = __floats2half2_rn(a.z, a.w);
        u.h2[2] = __floats2half2_rn(b.x, b.y);
        u.h2[3] = __floats2half2_rn(b.z, b.w);
        dst[g] = u.f4;
    }
}

// ---- Exclusive scan over 4096 counts (1 block); writes offsets AND cursor ----
__global__ void scan_kernel(const int* __restrict__ counts, int* __restrict__ offsets,
                            int* __restrict__ cursor, int n_rows) {
    __shared__ int partial[256];
    const int t = threadIdx.x;
    const int per = (n_rows + 255) / 256;
    const int base = t * per;
    int sum = 0;
    for (int j = 0; j < per; ++j) {
        int idx = base + j;
        if (idx < n_rows) sum += counts[idx];
    }
    partial[t] = sum;
    __syncthreads();
    for (int off = 1; off < 256; off <<= 1) {
        int v = 0;
        if (t >= off) v = partial[t - off];
        __syncthreads();
        if (t >= off) partial[t] += v;
        __syncthreads();
    }
    int run = (t == 0) ? 0 : partial[t - 1];
    for (int j = 0; j < per; ++j) {
        int idx = base + j;
        if (idx < n_rows) {
            offsets[idx] = run;
            cursor[idx] = run;
            run += counts[idx];
        }
    }
    if (t == 255) offsets[n_rows] = run;
}

// ---- Scatter nnz into row-sorted (col,val) pairs ----
__global__ void scatter_pairs_kernel(const int* __restrict__ rows, const int* __restrict__ cols,
                                     const float* __restrict__ values, int* __restrict__ cursor,
                                     int2* __restrict__ pairs, int nnz) {
    int i = blockIdx.x * blockDim.x + threadIdx.x;
    if (i < nnz) {
        int p = atomicAdd(&cursor[rows[i]], 1);
        pairs[p] = make_int2(cols[i], __float_as_int(values[i]));
    }
}

// ---- Accumulate: one wave per output row, lane covers 8 fp16 cols (16B gather) ----
__global__ __launch_bounds__(256) void accum_f16_kernel(
    const __half* __restrict__ wf16, const float* __restrict__ bias,
    const int* __restrict__ offsets, const int2* __restrict__ pairs,
    float* __restrict__ out, int out_f) {
    const int wave = threadIdx.x >> 6;
    const int lane = threadIdx.x & 63;
    const int row = blockIdx.x * 4 + wave;
    const int start = offsets[row];
    const int end = offsets[row + 1];

    const float4* wbase = (const float4*)wf16;   // one float4 = 8 halfs
    float acc[8] = {0.f, 0.f, 0.f, 0.f, 0.f, 0.f, 0.f, 0.f};

    int p = start;
    for (; p + 2 <= end; p += 2) {
        int2 e0 = pairs[p];
        int2 e1 = pairs[p + 1];
        float v0 = __int_as_float(e0.y);
        float v1 = __int_as_float(e1.y);
        float4 w0 = wbase[(long long)e0.x * 64 + lane];
        float4 w1 = wbase[(long long)e1.x * 64 + lane];
        const __half2* h0 = (const __half2*)&w0;
        const __half2* h1 = (const __half2*)&w1;
#pragma unroll
        for (int j = 0; j < 4; ++j) {
            float2 f0 = __half22float2(h0[j]);
            float2 f1 = __half22float2(h1[j]);
            acc[2 * j]     += v0 * f0.x + v1 * f1.x;
            acc[2 * j + 1] += v0 * f0.y + v1 * f1.y;
        }
    }
    if (p < end) {
        int2 e0 = pairs[p];
        float v0 = __int_as_float(e0.y);
        float4 w0 = wbase[(long long)e0.x * 64 + lane];
        const __half2* h0 = (const __half2*)&w0;
#pragma unroll
        for (int j = 0; j < 4; ++j) {
            float2 f0 = __half22float2(h0[j]);
            acc[2 * j]     += v0 * f0.x;
            acc[2 * j + 1] += v0 * f0.y;
        }
    }

    const int colbase = lane * 8;
    float4 b0 = ((const float4*)(bias + colbase))[0];
    float4 b1 = ((const float4*)(bias + colbase))[1];
    float4 o0 = make_float4(acc[0] + b0.x, acc[1] + b0.y, acc[2] + b0.z, acc[3] + b0.w);
    float4 o1 = make_float4(acc[4] + b1.x, acc[5] + b1.y, acc[6] + b1.z, acc[7] + b1.w);
    float4* orow = (float4*)(out + (long long)row * out_f + colbase);
    orow[0] = o0;
    orow[1] = o1;
}

// ================= Fallback path (ws too small): round-1 f32 scheme =================
__global__ void count_rows_kernel(const int* __restrict__ rows, int* __restrict__ counts, int nnz) {
    int i = blockIdx.x * blockDim.x + threadIdx.x;
    if (i < nnz) atomicAdd(&counts[rows[i]], 1);
}
__global__ void scatter_kernel(const int* __restrict__ rows, int* __restrict__ cursor,
                               int* __restrict__ perm, int nnz) {
    int i = blockIdx.x * blockDim.x + threadIdx.x;
    if (i < nnz) {
        int p = atomicAdd(&cursor[rows[i]], 1);
        perm[p] = i;
    }
}
__global__ void accum_kernel(const float* __restrict__ values, const float* __restrict__ weight,
                             const float* __restrict__ bias, const int* __restrict__ cols,
                             const int* __restrict__ offsets, const int* __restrict__ perm,
                             float* __restrict__ out, int out_f) {
    const int r = blockIdx.x;
    const int start = offsets[r];
    const int end = offsets[r + 1];
    const int step = blockDim.x * 4;
    for (int base = threadIdx.x * 4; base < out_f; base += step) {
        float4 acc = make_float4(0.f, 0.f, 0.f, 0.f);
        for (int p = start; p < end; ++p) {
            int k = perm[p];
            float v = values[k];
            long long c = cols[k];
            float4 w = *(const float4*)(weight + c * (long long)out_f + base);
            acc.x += v * w.x; acc.y += v * w.y; acc.z += v * w.z; acc.w += v * w.w;
        }
        float4 b = *(const float4*)(bias + base);
        acc.x += b.x; acc.y += b.y; acc.z += b.z; acc.w += b.w;
        *(float4*)(out + (long long)r * out_f + base) = acc;
    }
}

static size_t align_up(size_t x, size_t a) { return (x + a - 1) & ~(a - 1); }

extern "C" void kernel_launch(void* const* d_in, const int* in_sizes, int n_in,
                              void* d_out, int out_size, void* d_ws, size_t ws_size,
                              hipStream_t stream) {
    const float* values = (const float*)d_in[0];
    const float* weight = (const float*)d_in[1];
    const float* bias   = (const float*)d_in[2];
    const int*   rows   = (const int*)d_in[3];
    const int*   cols   = (const int*)d_in[4];

    const int nnz = in_sizes[0];
    const long long wtotal = in_sizes[1];
    const int out_f = in_sizes[2];
    const int n_rows = out_size / out_f;
    float* out = (float*)d_out;

    // ws layout: wf16[wtotal] | counts[n_rows] | offsets[n_rows+1] | cursor[n_rows] | pairs[nnz]
    size_t off_wf16 = 0;
    size_t off_counts = align_up(off_wf16 + (size_t)wtotal * sizeof(__half), 256);
    size_t off_offsets = off_counts + (size_t)n_rows * sizeof(int);
    size_t off_cursor = off_offsets + (size_t)(n_rows + 1) * sizeof(int);
    size_t off_pairs = align_up(off_cursor + (size_t)n_rows * sizeof(int), 256);
    size_t need = off_pairs + (size_t)nnz * sizeof(int2);

    if (ws_size >= need && (out_f % 512) == 0) {
        char* ws = (char*)d_ws;
        __half* wf16 = (__half*)(ws + off_wf16);
        int* counts = (int*)(ws + off_counts);
        int* offsets = (int*)(ws + off_offsets);
        int* cursor = (int*)(ws + off_cursor);
        int2* pairs = (int2*)(ws + off_pairs);

        hipMemsetAsync(counts, 0, (size_t)n_rows * sizeof(int), stream);

        long long ngroups = wtotal / 8;
        int cc_blocks = (int)((ngroups + 255) / 256);
        convert_count_kernel<<<cc_blocks, 256, 0, stream>>>(weight, wf16, ngroups,
                                                            rows, counts, nnz);
        scan_kernel<<<1, 256, 0, stream>>>(counts, offsets, cursor, n_rows);
        int sc_blocks = (nnz + 255) / 256;
        scatter_pairs_kernel<<<sc_blocks, 256, 0, stream>>>(rows, cols, values, cursor,
                                                            pairs, nnz);
        accum_f16_kernel<<<n_rows / 4, 256, 0, stream>>>(wf16, bias, offsets, pairs,
                                                         out, out_f);
    } else {
        // f32 fallback: counts | offsets | cursor | perm
        int* counts = (int*)d_ws;
        int* offsets = counts + n_rows;
        int* cursor = offsets + n_rows + 1;
        int* perm = cursor + n_rows;
        hipMemsetAsync(counts, 0, (size_t)n_rows * sizeof(int), stream);
        int blocks = (nnz + 255) / 256;
        count_rows_kernel<<<blocks, 256, 0, stream>>>(rows, counts, nnz);
        scan_kernel<<<1, 256, 0, stream>>>(counts, offsets, cursor, n_rows);
        scatter_kernel<<<blocks, 256, 0, stream>>>(rows, cursor, perm, nnz);
        accum_kernel<<<n_rows, 128, 0, stream>>>(values, weight, bias, cols,
                                                 offsets, perm, out, out_f);
    }
}